// Round 2
// baseline (825.900 us; speedup 1.0000x reference)
//
#include <hip/hip_runtime.h>
#include <math.h>

#define D_MODEL 2048
#define NEXP    64
#define NROWS   32768
#define SPLITS  4                   // waves per block = K-splits
#define KSPL    (D_MODEL / SPLITS)  // 512 k per wave
#define GRP     16                  // k per inner group = 64B (one line) per lane
#define BM      64                  // rows per block (= lanes per wave)

// Lane = one row, all 64 experts accumulated in VGPRs (acc[64]).
// W[e][k] is wave-uniform -> scalar loads (s_load_dwordx16), FMA reads SGPR.
// x streamed from global: one 64B line per lane per 16-k group, no LDS in loop.
// 4 waves split K; deterministic LDS reduction + top-2 epilogue per block.
// 512 blocks x 4 waves = 2048 waves = 8 waves/CU (LDS 66.5KB -> 2 blocks/CU).
__global__ __launch_bounds__(256, 2) void router_kernel(
    const float* __restrict__ x,      // [NROWS, D_MODEL]
    const float* __restrict__ gw,     // [NEXP, D_MODEL]
    const float* __restrict__ bias,   // [NEXP]
    float* __restrict__ out)          // [2*NROWS weights][2*NROWS idx-as-float]
{
    __shared__ float red[SPLITS][BM][NEXP + 1];  // +1 pad: epilogue column reads conflict-free

    const int t    = threadIdx.x;
    const int lane = t & 63;
    const int wv   = t >> 6;                     // k-split id 0..3
    const int row  = blockIdx.x * BM + lane;

    const float* xp  = x  + (size_t)row * D_MODEL + wv * KSPL;
    const float* wp0 = gw + wv * KSPL;           // wave-uniform base

    float acc[NEXP];
#pragma unroll
    for (int e = 0; e < NEXP; ++e) acc[e] = 0.f;

    float4 xa[4], xb[4];
#pragma unroll
    for (int q = 0; q < 4; ++q) xa[q] = ((const float4*)xp)[q];   // group 0

    for (int g = 0; g < KSPL; g += GRP) {
        // prefetch next 64B line per lane; HBM latency hides under 1024 FMAs
        if (g + GRP < KSPL) {
#pragma unroll
            for (int q = 0; q < 4; ++q)
                xb[q] = ((const float4*)(xp + g + GRP))[q];
        }
        const float* xf = (const float*)xa;      // SROA keeps this in VGPRs
#pragma unroll
        for (int e = 0; e < NEXP; ++e) {
            const float* wp = wp0 + (size_t)e * D_MODEL + g;  // uniform -> s_load
#pragma unroll
            for (int j = 0; j < GRP; ++j)
                acc[e] = fmaf(xf[j], wp[j], acc[e]);
        }
#pragma unroll
        for (int q = 0; q < 4; ++q) xa[q] = xb[q];
    }

    // deposit this wave's K-partial: red[wv][lane][0..63]
#pragma unroll
    for (int e = 0; e < NEXP; e += 4) {
        float4 v = make_float4(acc[e], acc[e + 1], acc[e + 2], acc[e + 3]);
        *(float4*)&red[wv][lane][e] = v;
    }
    __syncthreads();

    // epilogue: one thread per row (threads 0..63); lanes stride 65 floats -> no conflicts
    if (t < BM) {
        const int grow = blockIdx.x * BM + t;
        float m1 = -INFINITY, m2 = -INFINITY;
        int   e1 = 0, e2 = 0;
        // pass 1: combine partials (fixed split order: deterministic), top-2 scan
        for (int e = 0; e < NEXP; ++e) {
            float l = ((red[0][t][e] + red[1][t][e]) + red[2][t][e]) + red[3][t][e]
                      + bias[e];
            red[0][t][e] = l;                    // stash combined logit for pass 2
            if (l > m1) { m2 = m1; e2 = e1; m1 = l; e1 = e; }
            else if (l > m2) { m2 = l; e2 = e; }
        }
        // pass 2: full softmax denominator (max-subtracted), as reference
        float z = 0.f;
        for (int e = 0; e < NEXP; ++e)
            z += expf(red[0][t][e] - m1);
        const float p2    = expf(m2 - m1);
        const float denom = (1.f + p2) + 1e-8f * z;
        out[grow * 2 + 0] = 1.f / denom;
        out[grow * 2 + 1] = p2 / denom;
        float* oidx = out + 2 * NROWS;
        oidx[grow * 2 + 0] = (float)e1;
        oidx[grow * 2 + 1] = (float)e2;
    }
}

extern "C" void kernel_launch(void* const* d_in, const int* in_sizes, int n_in,
                              void* d_out, int out_size, void* d_ws, size_t ws_size,
                              hipStream_t stream) {
    const float* x    = (const float*)d_in[0];   // [32768, 2048]
    const float* gw   = (const float*)d_in[1];   // [64, 2048]
    const float* bias = (const float*)d_in[2];   // [64]
    float* out = (float*)d_out;                  // 131072 floats
    (void)in_sizes; (void)n_in; (void)out_size; (void)d_ws; (void)ws_size;

    dim3 grid(NROWS / BM);   // 512
    dim3 block(256);
    router_kernel<<<grid, block, 0, stream>>>(x, gw, bias, out);
}

// Round 3
// 783.398 us; speedup vs baseline: 1.0543x; 1.0543x over previous
//
#include <hip/hip_runtime.h>
#include <math.h>

#define D_MODEL 2048
#define NEXP    64
#define NROWS   32768
#define SPLITS  4                   // waves per block = K-splits
#define KSPL    (D_MODEL / SPLITS)  // 512 k per wave
#define GRP     16                  // k per inner group = 64B (one line) per lane
#define BM      64                  // rows per block (= lanes per wave)

// Lane = one row, all 64 experts accumulated in VGPRs (acc[64]).
// W offset made provably wave-uniform via readfirstlane -> backend emits
// SMEM s_load (merged to dwordx16); v_fma reads the SGPR operand for free.
// x streamed per-lane from global: one 64B line per lane per 16-k group.
// 4 waves split K; deterministic LDS reduction + top-2 epilogue per block.
__global__ __launch_bounds__(256, 2) void router_kernel(
    const float* __restrict__ x,      // [NROWS, D_MODEL]
    const float* __restrict__ gw,     // [NEXP, D_MODEL]
    const float* __restrict__ bias,   // [NEXP]
    float* __restrict__ out)          // [2*NROWS weights][2*NROWS idx-as-float]
{
    __shared__ float red[SPLITS][BM][NEXP + 1];  // +1 pad: conflict-free epilogue

    const int t    = threadIdx.x;
    const int lane = t & 63;
    const int wv   = t >> 6;                     // k-split id 0..3 (wave-uniform)
    const int row  = blockIdx.x * BM + lane;

    // readfirstlane: LLVM's uniformity analysis can't see that t>>6 is
    // wave-uniform; this makes it provable -> scalar (SMEM) W loads.
    const int koff = __builtin_amdgcn_readfirstlane(wv * KSPL);

    const float* xp  = x  + (size_t)row * D_MODEL + koff;
    const float* wp0 = gw + koff;                // uniform base

    float acc[NEXP];
#pragma unroll
    for (int e = 0; e < NEXP; ++e) acc[e] = 0.f;

    // x double-buffer in registers; constant indices only (SROA-safe)
    float xa[GRP], xb[GRP];
#pragma unroll
    for (int q = 0; q < 4; ++q) {
        const float4 v = ((const float4*)xp)[q];
        xa[4 * q + 0] = v.x; xa[4 * q + 1] = v.y;
        xa[4 * q + 2] = v.z; xa[4 * q + 3] = v.w;
    }

    for (int g = 0; g < KSPL; g += GRP) {
        if (g + GRP < KSPL) {                    // prefetch next 64B line per lane
#pragma unroll
            for (int q = 0; q < 4; ++q) {
                const float4 v = ((const float4*)(xp + g + GRP))[q];
                xb[4 * q + 0] = v.x; xb[4 * q + 1] = v.y;
                xb[4 * q + 2] = v.z; xb[4 * q + 3] = v.w;
            }
        }
#pragma unroll
        for (int e = 0; e < NEXP; ++e) {
            const float* wp = wp0 + e * D_MODEL + g;  // uniform -> s_load_dwordx16
#pragma unroll
            for (int j = 0; j < GRP; ++j)
                acc[e] = fmaf(xa[j], wp[j], acc[e]);
        }
#pragma unroll
        for (int j = 0; j < GRP; ++j) xa[j] = xb[j];
    }

    // deposit this wave's K-partial: red[wv][lane][0..63]
#pragma unroll
    for (int e = 0; e < NEXP; e += 4) {
        const float4 v = make_float4(acc[e], acc[e + 1], acc[e + 2], acc[e + 3]);
        *(float4*)&red[wv][lane][e] = v;
    }
    __syncthreads();

    // epilogue: one thread per row (threads 0..63); rows stride 65 floats
    if (t < BM) {
        const int grow = blockIdx.x * BM + t;
        float m1 = -INFINITY, m2 = -INFINITY;
        int   e1 = 0, e2 = 0;
        // combine partials in fixed split order (deterministic), top-2 scan
        for (int e = 0; e < NEXP; ++e) {
            const float l = ((red[0][t][e] + red[1][t][e]) + red[2][t][e])
                            + red[3][t][e] + bias[e];
            red[0][t][e] = l;                    // stash for pass 2
            if (l > m1) { m2 = m1; e2 = e1; m1 = l; e1 = e; }
            else if (l > m2) { m2 = l; e2 = e; }
        }
        // full softmax denominator (max-subtracted), as reference
        float z = 0.f;
        for (int e = 0; e < NEXP; ++e)
            z += expf(red[0][t][e] - m1);
        const float p2    = expf(m2 - m1);
        const float denom = (1.f + p2) + 1e-8f * z;
        out[grow * 2 + 0] = 1.f / denom;
        out[grow * 2 + 1] = p2 / denom;
        float* oidx = out + 2 * NROWS;
        oidx[grow * 2 + 0] = (float)e1;
        oidx[grow * 2 + 1] = (float)e2;
    }
}

extern "C" void kernel_launch(void* const* d_in, const int* in_sizes, int n_in,
                              void* d_out, int out_size, void* d_ws, size_t ws_size,
                              hipStream_t stream) {
    const float* x    = (const float*)d_in[0];   // [32768, 2048]
    const float* gw   = (const float*)d_in[1];   // [64, 2048]
    const float* bias = (const float*)d_in[2];   // [64]
    float* out = (float*)d_out;                  // 131072 floats
    (void)in_sizes; (void)n_in; (void)out_size; (void)d_ws; (void)ws_size;

    dim3 grid(NROWS / BM);   // 512
    dim3 block(256);
    router_kernel<<<grid, block, 0, stream>>>(x, gw, bias, out);
}